// Round 1
// baseline (708.972 us; speedup 1.0000x reference)
//
#include <hip/hip_runtime.h>
#include <math.h>

#define NEG_SLOPE 0.2f

typedef short short8 __attribute__((ext_vector_type(8)));
typedef float float4v __attribute__((ext_vector_type(4)));
typedef _Float16 h8 __attribute__((ext_vector_type(8)));

__device__ __forceinline__ unsigned short f2bf(float f) {
    unsigned u = __float_as_uint(f);
    unsigned r = (u + 0x7fff + ((u >> 16) & 1)) >> 16;
    return (unsigned short)r;
}
__device__ __forceinline__ float bf2f(unsigned short h) {
    return __uint_as_float(((unsigned)h) << 16);
}
__device__ __forceinline__ unsigned short f2h(float f) {
    _Float16 t = (_Float16)f;
    return *(unsigned short*)&t;
}

// async global->LDS, 16B per lane. ldsptr must be wave-uniform; HW adds lane*16.
__device__ __forceinline__ void gload_lds16(const void* g, void* l) {
    __builtin_amdgcn_global_load_lds(
        (const __attribute__((address_space(1))) unsigned int*)g,
        (__attribute__((address_space(3))) unsigned int*)l, 16, 0, 0);
}

// ======================= CSR build (by dst) =======================

__global__ void count_kernel(const int* __restrict__ dst, int E, int* __restrict__ counts) {
    int i = blockIdx.x * blockDim.x + threadIdx.x;
    if (i < E) atomicAdd(&counts[dst[i]], 1);
}

__global__ void scan1_kernel(const int* __restrict__ in, int n, int* __restrict__ bsums) {
    __shared__ int sdata[256];
    int tid = threadIdx.x;
    int base = blockIdx.x * 1024 + tid * 4;
    int s = 0;
#pragma unroll
    for (int j = 0; j < 4; ++j) if (base + j < n) s += in[base + j];
    sdata[tid] = s; __syncthreads();
    for (int off = 128; off > 0; off >>= 1) {
        if (tid < off) sdata[tid] += sdata[tid + off];
        __syncthreads();
    }
    if (tid == 0) bsums[blockIdx.x] = sdata[0];
}

// parallel exclusive scan of nb (<=128) block sums
__global__ void scan2_kernel(int* bsums, int nb) {
    __shared__ int sd[128];
    int tid = threadIdx.x;
    int v = (tid < nb) ? bsums[tid] : 0;
    sd[tid] = v; __syncthreads();
    for (int off = 1; off < 128; off <<= 1) {
        int t = (tid >= off) ? sd[tid - off] : 0;
        __syncthreads();
        sd[tid] += t;
        __syncthreads();
    }
    if (tid < nb) bsums[tid] = sd[tid] - v;  // exclusive
}

__global__ void scan3_kernel(const int* __restrict__ in, int n, const int* __restrict__ bsums,
                             int* __restrict__ row_ptr, int* __restrict__ cursor, int E) {
    __shared__ int sdata[256];
    int tid = threadIdx.x;
    int base = blockIdx.x * 1024 + tid * 4;
    int v[4]; int s = 0;
#pragma unroll
    for (int j = 0; j < 4; ++j) { v[j] = (base + j < n) ? in[base + j] : 0; s += v[j]; }
    sdata[tid] = s; __syncthreads();
    for (int off = 1; off < 256; off <<= 1) {
        int t = (tid >= off) ? sdata[tid - off] : 0;
        __syncthreads();
        sdata[tid] += t;
        __syncthreads();
    }
    int excl = sdata[tid] - s;
    int run = bsums[blockIdx.x] + excl;
#pragma unroll
    for (int j = 0; j < 4; ++j) {
        if (base + j < n) { row_ptr[base + j] = run; cursor[base + j] = run; run += v[j]; }
    }
    if (blockIdx.x == 0 && tid == 0) row_ptr[n] = E;
}

__global__ void fill_kernel(const int* __restrict__ dst, const int* __restrict__ src, int E,
                            int* __restrict__ cursor, int* __restrict__ sperm) {
    int i = blockIdx.x * blockDim.x + threadIdx.x;
    if (i < E) {
        int p = atomicAdd(&cursor[dst[i]], 1);
        sperm[p] = src[i];
    }
}

// ======================= prep: all weight transposes + waSD dots, one dispatch =======================

__global__ __launch_bounds__(256) void prep_kernel(
    const float* __restrict__ W0, const float* __restrict__ W1, const float* __restrict__ W2,
    const float* __restrict__ a0, const float* __restrict__ a1, const float* __restrict__ a2,
    unsigned short* __restrict__ WT0, unsigned short* __restrict__ WT1, unsigned short* __restrict__ WT2,
    unsigned short* __restrict__ wa0, unsigned short* __restrict__ wa1, unsigned short* __restrict__ wa2) {
    int i = blockIdx.x * 256 + threadIdx.x;
    if (i < 32768) {                    // W0 [128][256] -> WT0 [256][128]
        int k = i >> 8, n = i & 255;
        WT0[n * 128 + k] = f2bf(W0[i]);
    } else if (i < 98304) {             // W1 [256][256] -> WT1 [256][256]
        int j = i - 32768;
        int k = j >> 8, n = j & 255;
        WT1[n * 256 + k] = f2bf(W1[j]);
    } else if (i < 114688) {            // W2 [256][64] -> WT2 [64][256]
        int j = i - 98304;
        int k = j >> 6, n = j & 63;
        WT2[n * 256 + k] = f2bf(W2[j]);
    } else if (i < 114688 + 2048) {     // wa0 [16][128]
        int t = i - 114688;
        int k = t >> 4, j8 = t & 15;
        float s = 0.f;
        if (j8 < 8) {
            int h = j8 & 3, off = (j8 >> 2) * 64;
            for (int d = 0; d < 64; ++d)
                s += W0[k * 256 + h * 64 + d] * a0[h * 128 + off + d];
        }
        wa0[j8 * 128 + k] = f2bf(s);
    } else if (i < 114688 + 2048 + 4096) {  // wa1 [16][256]
        int t = i - 114688 - 2048;
        int k = t >> 4, j8 = t & 15;
        float s = 0.f;
        if (j8 < 8) {
            int h = j8 & 3, off = (j8 >> 2) * 64;
            for (int d = 0; d < 64; ++d)
                s += W1[k * 256 + h * 64 + d] * a1[h * 128 + off + d];
        }
        wa1[j8 * 256 + k] = f2bf(s);
    } else if (i < 114688 + 2048 + 4096 + 4096) {  // wa2 [16][256]
        int t = i - 114688 - 2048 - 4096;
        int k = t >> 4, j8 = t & 15;
        float s = 0.f;
        if (j8 < 2) {
            for (int d = 0; d < 64; ++d)
                s += W2[k * 64 + d] * a2[j8 * 64 + d];
        }
        wa2[j8 * 256 + k] = f2bf(s);
    }
}

// fp32 -> bf16 elementwise (layer-0 input)
__global__ void xcvt_kernel(const float* __restrict__ X, unsigned short* __restrict__ b, int total) {
    int i = blockIdx.x * 256 + threadIdx.x;
    if (i >= total) return;
    b[i] = f2bf(X[i]);
}

// ======================= fused MFMA GEMM + alpha-via-MFMA + fp16-emit =======================

template <int BN>
__global__ __launch_bounds__(256) void gemm_fused(
    const unsigned short* __restrict__ A, const unsigned short* __restrict__ WT,
    const unsigned short* __restrict__ waSDT,
    unsigned short* __restrict__ hf16,
    float* __restrict__ as_, float* __restrict__ ad_,
    int M, int K) {
    __shared__ unsigned short AL[128 * 32];
    __shared__ unsigned short BL[BN * 32];
    __shared__ unsigned short WaL[16 * 32];

    int t = threadIdx.x;
    int w = t >> 6, lane = t & 63;
    int q = lane >> 4, i16 = lane & 15;
    int rowBase = blockIdx.x * 128;
    int colBase = blockIdx.y * BN;

    constexpr int MT = (BN == 128) ? 4 : 2;
    int wrow = (BN == 128) ? (w >> 1) * 64 : w * 32;
    int wcol = (BN == 128) ? (w & 1) * 64 : 0;

    bool alphaBlk = (blockIdx.y == 0);
    bool alphaWave = alphaBlk && ((BN == 64) || ((w & 1) == 0));

    float4v acc[MT][4];
    float4v accA[MT];
#pragma unroll
    for (int mt = 0; mt < MT; ++mt) {
        accA[mt] = (float4v)(0.f);
#pragma unroll
        for (int nt = 0; nt < 4; ++nt) acc[mt][nt] = (float4v)(0.f);
    }

    int srow = t >> 2;          // 0..63
    int skq = (t & 3) * 8;      // k offset in shorts (16B chunks)

    for (int k0 = 0; k0 < K; k0 += 32) {
        gload_lds16(A + (size_t)(rowBase + srow) * K + k0 + skq, AL + w * 512);
        gload_lds16(A + (size_t)(rowBase + 64 + srow) * K + k0 + skq, AL + 2048 + w * 512);
        gload_lds16(WT + (size_t)(colBase + srow) * K + k0 + skq, BL + w * 512);
        if (BN == 128)
            gload_lds16(WT + (size_t)(colBase + 64 + srow) * K + k0 + skq, BL + 2048 + w * 512);
        if (alphaBlk && w == 0)  // 16 rows x 32 k = 1 KB = one wave's gload
            gload_lds16(waSDT + (size_t)srow * K + k0 + skq, WaL);
        __syncthreads();

        short8 af[MT], bf[4];
#pragma unroll
        for (int mt = 0; mt < MT; ++mt)
            af[mt] = *(short8*)&AL[(wrow + mt * 16 + i16) * 32 + q * 8];
#pragma unroll
        for (int nt = 0; nt < 4; ++nt)
            bf[nt] = *(short8*)&BL[(wcol + nt * 16 + i16) * 32 + q * 8];
#pragma unroll
        for (int mt = 0; mt < MT; ++mt)
#pragma unroll
            for (int nt = 0; nt < 4; ++nt)
                acc[mt][nt] = __builtin_amdgcn_mfma_f32_16x16x32_bf16(af[mt], bf[nt], acc[mt][nt], 0, 0, 0);
        if (alphaWave) {
            short8 aw = *(short8*)&WaL[i16 * 32 + q * 8];
#pragma unroll
            for (int mt = 0; mt < MT; ++mt)
                accA[mt] = __builtin_amdgcn_mfma_f32_16x16x32_bf16(af[mt], aw, accA[mt], 0, 0, 0);
        }
        __syncthreads();
    }

    // ---- epilogue: C/D layout col=lane&15, row=q*4+r ----
    int cb0 = colBase + wcol;
#pragma unroll
    for (int mt = 0; mt < MT; ++mt)
#pragma unroll
        for (int r = 0; r < 4; ++r) {
            int grow = rowBase + wrow + mt * 16 + q * 4 + r;
            bool ok = grow < M;
            if (ok) {
#pragma unroll
                for (int nt = 0; nt < 4; ++nt) {
                    float v = acc[mt][nt][r];
                    if (BN == 128) hf16[(size_t)grow * 256 + cb0 + nt * 16 + i16] = f2h(v);
                    else           hf16[(size_t)grow * 64 + nt * 16 + i16] = f2h(v);
                }
                if (alphaWave) {
                    float av = accA[mt][r];
                    if (BN == 128) {
                        if (i16 < 4)      as_[grow * 4 + i16] = av;
                        else if (i16 < 8) ad_[grow * 4 + (i16 - 4)] = av;
                    } else {
                        if (i16 == 0)      as_[grow] = av;
                        else if (i16 == 1) ad_[grow] = av;
                    }
                }
            }
        }
}

// ======================= aggregate H=4: TWO nodes per wave, 8 loads in flight =======================
// Latency-bound gather: interleave two nodes' dependent chains (sperm->as_->exp->bpermute->h load)
// per wave. Tails are zero-padded (att=0, src=0 -> row 0, L1-resident) so the inner body is
// branch-free straight-line code and the scheduler hoists all 8 global loads ahead of the fmas.

__global__ __launch_bounds__(256) void aggregate4(
    const unsigned short* __restrict__ hf16, const int* __restrict__ row_ptr,
    const int* __restrict__ sperm, const float* __restrict__ as_, const float* __restrict__ ad_,
    unsigned short* __restrict__ outB, int n) {
    int w = threadIdx.x >> 6, lane = threadIdx.x & 63;
    int nodeA = blockIdx.x * 8 + w * 2;
    if (nodeA >= n) return;
    int nodeB = nodeA + 1;
    bool hasB = nodeB < n;

    int begA = row_ptr[nodeA];
    int degA = row_ptr[nodeA + 1] - begA;
    int begB = 0, degB = 0;
    if (hasB) { begB = row_ptr[nodeB]; degB = row_ptr[nodeB + 1] - begB; }

    int myh = lane & 3;
    float adA = ad_[nodeA * 4 + myh];
    float adB = hasB ? ad_[nodeB * 4 + myh] : 0.f;

    int half = lane >> 5;     // edge parity this lane aggregates
    int dg = lane & 31;       // dim group: dims dg*8..dg*8+7
    int hh = dg >> 3;         // head of those dims
    float accA[8], accB[8];
#pragma unroll
    for (int k = 0; k < 8; ++k) { accA[k] = 0.f; accB[k] = 0.f; }
    float lsumA = 0.f, lsumB = 0.f;

    const char* hbase = (const char*)hf16;
    unsigned dgo = (unsigned)dg << 4;
    int eSlot = lane >> 2;

    int degM = degA > degB ? degA : degB;
    for (int el0 = 0; el0 < degM; el0 += 16) {
        int neA = degA - el0; if (neA > 16) neA = 16;   // may be <= 0
        int neB = degB - el0; if (neB > 16) neB = 16;

        float attA = 0.f; int sAr = 0;
        if (eSlot < neA) {
            sAr = sperm[begA + el0 + eSlot];
            float e = as_[sAr * 4 + myh] + adA;
            e = e > 0.f ? e : NEG_SLOPE * e;
            attA = __expf(e);
        }
        float attB = 0.f; int sBr = 0;
        if (eSlot < neB) {
            sBr = sperm[begB + el0 + eSlot];
            float e = as_[sBr * 4 + myh] + adB;
            e = e > 0.f ? e : NEG_SLOPE * e;
            attB = __expf(e);
        }
        lsumA += attA; lsumB += attB;

        auto sub8 = [&](int j) {
            // slots j+half, j+2+half, j+4+half, j+6+half; pad slots have att==0, s==0 (row 0)
            int sl0 = (j + half) * 4, sl1 = (j + 2 + half) * 4,
                sl2 = (j + 4 + half) * 4, sl3 = (j + 6 + half) * 4;
            float aA0 = __shfl(attA, sl0 + hh, 64);
            float aA1 = __shfl(attA, sl1 + hh, 64);
            float aA2 = __shfl(attA, sl2 + hh, 64);
            float aA3 = __shfl(attA, sl3 + hh, 64);
            int   sA0 = __shfl(sAr, sl0, 64);
            int   sA1 = __shfl(sAr, sl1, 64);
            int   sA2 = __shfl(sAr, sl2, 64);
            int   sA3 = __shfl(sAr, sl3, 64);
            float aB0 = __shfl(attB, sl0 + hh, 64);
            float aB1 = __shfl(attB, sl1 + hh, 64);
            float aB2 = __shfl(attB, sl2 + hh, 64);
            float aB3 = __shfl(attB, sl3 + hh, 64);
            int   sB0 = __shfl(sBr, sl0, 64);
            int   sB1 = __shfl(sBr, sl1, 64);
            int   sB2 = __shfl(sBr, sl2, 64);
            int   sB3 = __shfl(sBr, sl3, 64);
            h8 vA0 = *(const h8*)(hbase + (((unsigned)sA0 << 9) + dgo));
            h8 vA1 = *(const h8*)(hbase + (((unsigned)sA1 << 9) + dgo));
            h8 vA2 = *(const h8*)(hbase + (((unsigned)sA2 << 9) + dgo));
            h8 vA3 = *(const h8*)(hbase + (((unsigned)sA3 << 9) + dgo));
            h8 vB0 = *(const h8*)(hbase + (((unsigned)sB0 << 9) + dgo));
            h8 vB1 = *(const h8*)(hbase + (((unsigned)sB1 << 9) + dgo));
            h8 vB2 = *(const h8*)(hbase + (((unsigned)sB2 << 9) + dgo));
            h8 vB3 = *(const h8*)(hbase + (((unsigned)sB3 << 9) + dgo));
#pragma unroll
            for (int k = 0; k < 8; ++k) accA[k] += aA0 * (float)vA0[k];
#pragma unroll
            for (int k = 0; k < 8; ++k) accA[k] += aA1 * (float)vA1[k];
#pragma unroll
            for (int k = 0; k < 8; ++k) accA[k] += aA2 * (float)vA2[k];
#pragma unroll
            for (int k = 0; k < 8; ++k) accA[k] += aA3 * (float)vA3[k];
#pragma unroll
            for (int k = 0; k < 8; ++k) accB[k] += aB0 * (float)vB0[k];
#pragma unroll
            for (int k = 0; k < 8; ++k) accB[k] += aB1 * (float)vB1[k];
#pragma unroll
            for (int k = 0; k < 8; ++k) accB[k] += aB2 * (float)vB2[k];
#pragma unroll
            for (int k = 0; k < 8; ++k) accB[k] += aB3 * (float)vB3[k];
        };
        sub8(0);
        if (neA > 8 || neB > 8) sub8(8);   // wave-uniform branch
    }

    // total denom per head: sum lanes with same (lane&3)
#pragma unroll
    for (int m = 4; m < 64; m <<= 1) {
        lsumA += __shfl_xor(lsumA, m, 64);
        lsumB += __shfl_xor(lsumB, m, 64);
    }
    float invA = 1.f / (lsumA + 1e-16f);
    float invB = 1.f / (lsumB + 1e-16f);
    float invhA = __shfl(invA, hh, 64);
    float invhB = __shfl(invB, hh, 64);

#pragma unroll
    for (int k = 0; k < 8; ++k) {
        accA[k] += __shfl_xor(accA[k], 32, 64);
        accB[k] += __shfl_xor(accB[k], 32, 64);
    }

    // half 0 writes node A, half 1 writes node B (all 64 lanes active)
    int nodeW = half ? nodeB : nodeA;
    if (nodeW < n) {
        float invW = half ? invhB : invhA;
        short8 hv;
#pragma unroll
        for (int k = 0; k < 8; ++k) {
            float o = (half ? accB[k] : accA[k]) * invW;
            o = o > 0.f ? o : expm1f(o);
            hv[k] = (short)f2bf(o);
        }
        *(short8*)(outB + (size_t)nodeW * 256 + dg * 8) = hv;
    }
}

// ======================= aggregate H=1: TWO nodes per wave, fp32 out (graded) =======================

__global__ __launch_bounds__(256) void aggregate1(
    const unsigned short* __restrict__ hf16, const int* __restrict__ row_ptr,
    const int* __restrict__ sperm, const float* __restrict__ as_, const float* __restrict__ ad_,
    float* __restrict__ out, int n) {
    int w = threadIdx.x >> 6, lane = threadIdx.x & 63;
    int nodeA = blockIdx.x * 8 + w * 2;
    if (nodeA >= n) return;
    int nodeB = nodeA + 1;
    bool hasB = nodeB < n;

    int begA = row_ptr[nodeA];
    int degA = row_ptr[nodeA + 1] - begA;
    int begB = 0, degB = 0;
    if (hasB) { begB = row_ptr[nodeB]; degB = row_ptr[nodeB + 1] - begB; }
    float adA = as_ ? 0.f : 0.f;  // placeholder to keep structure clear (unused)
    float adnA = ad_[nodeA];
    float adnB = hasB ? ad_[nodeB] : 0.f;
    (void)adA;

    int eg = lane >> 3;   // edge slot within 8-edge subgroup
    int dg = lane & 7;    // dims dg*8..+8
    float accA[8], accB[8];
#pragma unroll
    for (int k = 0; k < 8; ++k) { accA[k] = 0.f; accB[k] = 0.f; }
    float lsumA = 0.f, lsumB = 0.f;

    const char* hbase = (const char*)hf16;
    unsigned dgo = (unsigned)dg << 4;

    int degM = degA > degB ? degA : degB;
    for (int el0 = 0; el0 < degM; el0 += 64) {
        int neA = degA - el0; if (neA > 64) neA = 64;   // may be <= 0
        int neB = degB - el0; if (neB > 64) neB = 64;

        float attA = 0.f; int sAr = 0;
        if (lane < neA) {
            sAr = sperm[begA + el0 + lane];
            float e = as_[sAr] + adnA;
            e = e > 0.f ? e : NEG_SLOPE * e;
            attA = __expf(e);
        }
        float attB = 0.f; int sBr = 0;
        if (lane < neB) {
            sBr = sperm[begB + el0 + lane];
            float e = as_[sBr] + adnB;
            e = e > 0.f ? e : NEG_SLOPE * e;
            attB = __expf(e);
        }
        lsumA += attA; lsumB += attB;

        auto sub16 = [&](int j) {
            // slots j+eg, j+8+eg; pad slots have att==0, s==0 (row 0)
            int sl0 = j + eg, sl1 = j + 8 + eg;
            float aA0 = __shfl(attA, sl0, 64);
            float aA1 = __shfl(attA, sl1, 64);
            int   sA0 = __shfl(sAr, sl0, 64);
            int   sA1 = __shfl(sAr, sl1, 64);
            float aB0 = __shfl(attB, sl0, 64);
            float aB1 = __shfl(attB, sl1, 64);
            int   sB0 = __shfl(sBr, sl0, 64);
            int   sB1 = __shfl(sBr, sl1, 64);
            h8 vA0 = *(const h8*)(hbase + (((unsigned)sA0 << 7) + dgo));
            h8 vA1 = *(const h8*)(hbase + (((unsigned)sA1 << 7) + dgo));
            h8 vB0 = *(const h8*)(hbase + (((unsigned)sB0 << 7) + dgo));
            h8 vB1 = *(const h8*)(hbase + (((unsigned)sB1 << 7) + dgo));
#pragma unroll
            for (int k = 0; k < 8; ++k) accA[k] += aA0 * (float)vA0[k];
#pragma unroll
            for (int k = 0; k < 8; ++k) accA[k] += aA1 * (float)vA1[k];
#pragma unroll
            for (int k = 0; k < 8; ++k) accB[k] += aB0 * (float)vB0[k];
#pragma unroll
            for (int k = 0; k < 8; ++k) accB[k] += aB1 * (float)vB1[k];
        };
        sub16(0);
        if (neA > 16 || neB > 16) sub16(16);
        if (neA > 32 || neB > 32) sub16(32);
        if (neA > 48 || neB > 48) sub16(48);
    }

#pragma unroll
    for (int m = 1; m < 64; m <<= 1) {
        lsumA += __shfl_xor(lsumA, m, 64);
        lsumB += __shfl_xor(lsumB, m, 64);
    }
    float invA = 1.f / (lsumA + 1e-16f);
    float invB = 1.f / (lsumB + 1e-16f);

#pragma unroll
    for (int m = 8; m < 64; m <<= 1)
#pragma unroll
        for (int k = 0; k < 8; ++k) {
            accA[k] += __shfl_xor(accA[k], m, 64);
            accB[k] += __shfl_xor(accB[k], m, 64);
        }

    if (eg == 0) {
        float4 o0 = make_float4(accA[0] * invA, accA[1] * invA, accA[2] * invA, accA[3] * invA);
        float4 o1 = make_float4(accA[4] * invA, accA[5] * invA, accA[6] * invA, accA[7] * invA);
        *(float4*)(out + (size_t)nodeA * 64 + dg * 8) = o0;
        *(float4*)(out + (size_t)nodeA * 64 + dg * 8 + 4) = o1;
    } else if (eg == 1 && hasB) {
        float4 o0 = make_float4(accB[0] * invB, accB[1] * invB, accB[2] * invB, accB[3] * invB);
        float4 o1 = make_float4(accB[4] * invB, accB[5] * invB, accB[6] * invB, accB[7] * invB);
        *(float4*)(out + (size_t)nodeB * 64 + dg * 8) = o0;
        *(float4*)(out + (size_t)nodeB * 64 + dg * 8 + 4) = o1;
    }
}

// ======================= launch =======================

extern "C" void kernel_launch(void* const* d_in, const int* in_sizes, int n_in,
                              void* d_out, int out_size, void* d_ws, size_t ws_size,
                              hipStream_t stream) {
    const float* x  = (const float*)d_in[0];
    const int*   ei = (const int*)d_in[1];
    const float* W0 = (const float*)d_in[2];
    const float* a0 = (const float*)d_in[3];
    const float* W1 = (const float*)d_in[4];
    const float* a1 = (const float*)d_in[5];
    const float* W2 = (const float*)d_in[6];
    const float* a2 = (const float*)d_in[7];
    float* out = (float*)d_out;

    int N = in_sizes[0] / 128;
    int E = in_sizes[1] / 2;
    int Npad = (N + 127) & ~127;
    const int* srcp = ei;
    const int* dstp = ei + E;

    char* ws = (char*)d_ws;
    size_t off = 0;
    auto alloc = [&](size_t bytes) -> void* {
        void* p = ws + off;
        off += (bytes + 255) & ~(size_t)255;
        return p;
    };
    unsigned short* xbf  = (unsigned short*)alloc((size_t)Npad * 128 * 2);
    unsigned short* actB = (unsigned short*)alloc((size_t)Npad * 256 * 2);
    unsigned short* hf16 = (unsigned short*)alloc((size_t)Npad * 256 * 2);
    unsigned short* Cf16 = (unsigned short*)alloc((size_t)Npad * 64 * 2);
    float* as_    = (float*)alloc((size_t)N * 4 * 4);
    float* ad_    = (float*)alloc((size_t)N * 4 * 4);
    int*   counts = (int*)alloc((size_t)N * 4);
    int*   row_ptr= (int*)alloc((size_t)(N + 1) * 4);
    int*   cursor = (int*)alloc((size_t)N * 4);
    int*   sperm  = (int*)alloc((size_t)E * 4);
    unsigned short* WT0 = (unsigned short*)alloc((size_t)256 * 128 * 2);
    unsigned short* WT1 = (unsigned short*)alloc((size_t)256 * 256 * 2);
    unsigned short* WT2 = (unsigned short*)alloc((size_t)64 * 256 * 2);
    unsigned short* wa0 = (unsigned short*)alloc((size_t)16 * 128 * 2);
    unsigned short* wa1 = (unsigned short*)alloc((size_t)16 * 256 * 2);
    unsigned short* wa2 = (unsigned short*)alloc((size_t)16 * 256 * 2);
    int*   bsums  = (int*)alloc(4096);

    // ---- CSR by dst ----
    hipMemsetAsync(counts, 0, (size_t)N * 4, stream);
    int egrid = (E + 255) / 256;
    count_kernel<<<egrid, 256, 0, stream>>>(dstp, E, counts);
    int nb = (N + 1023) / 1024;
    scan1_kernel<<<nb, 256, 0, stream>>>(counts, N, bsums);
    scan2_kernel<<<1, 128, 0, stream>>>(bsums, nb);
    scan3_kernel<<<nb, 256, 0, stream>>>(counts, N, bsums, row_ptr, cursor, E);
    fill_kernel<<<egrid, 256, 0, stream>>>(dstp, srcp, E, cursor, sperm);

    // ---- prep: all W transposes + waSD, one dispatch ----
    prep_kernel<<<(114688 + 10240 + 255) / 256, 256, 0, stream>>>(
        W0, W1, W2, a0, a1, a2, WT0, WT1, WT2, wa0, wa1, wa2);
    xcvt_kernel<<<((N * 128) + 255) / 256, 256, 0, stream>>>(x, xbf, N * 128);

    int gemm_gx = Npad / 128;
    int ngrid8 = (N + 7) / 8;

    // ---- Layer 0 ----
    gemm_fused<128><<<dim3(gemm_gx, 2), 256, 0, stream>>>(xbf, WT0, wa0, hf16, as_, ad_, N, 128);
    aggregate4<<<ngrid8, 256, 0, stream>>>(hf16, row_ptr, sperm, as_, ad_, actB, N);

    // ---- Layer 1 ----
    gemm_fused<128><<<dim3(gemm_gx, 2), 256, 0, stream>>>(actB, WT1, wa1, hf16, as_, ad_, N, 256);
    aggregate4<<<ngrid8, 256, 0, stream>>>(hf16, row_ptr, sperm, as_, ad_, actB, N);

    // ---- Layer 2 ----
    gemm_fused<64><<<dim3(gemm_gx, 1), 256, 0, stream>>>(actB, WT2, wa2, Cf16, as_, ad_, N, 256);
    aggregate1<<<ngrid8, 256, 0, stream>>>(Cf16, row_ptr, sperm, as_, ad_, out, N);
}

// Round 3
// 705.884 us; speedup vs baseline: 1.0044x; 1.0044x over previous
//
#include <hip/hip_runtime.h>
#include <math.h>

#define NEG_SLOPE 0.2f

typedef short short8 __attribute__((ext_vector_type(8)));
typedef float float4v __attribute__((ext_vector_type(4)));
typedef _Float16 h8 __attribute__((ext_vector_type(8)));

__device__ __forceinline__ unsigned short f2bf(float f) {
    unsigned u = __float_as_uint(f);
    unsigned r = (u + 0x7fff + ((u >> 16) & 1)) >> 16;
    return (unsigned short)r;
}
__device__ __forceinline__ float bf2f(unsigned short h) {
    return __uint_as_float(((unsigned)h) << 16);
}
__device__ __forceinline__ unsigned short f2h(float f) {
    _Float16 t = (_Float16)f;
    return *(unsigned short*)&t;
}

// async global->LDS, 16B per lane. ldsptr must be wave-uniform; HW adds lane*16.
__device__ __forceinline__ void gload_lds16(const void* g, void* l) {
    __builtin_amdgcn_global_load_lds(
        (const __attribute__((address_space(1))) unsigned int*)g,
        (__attribute__((address_space(3))) unsigned int*)l, 16, 0, 0);
}

// ======================= CSR build (by dst) =======================

__global__ void count_kernel(const int* __restrict__ dst, int E, int* __restrict__ counts) {
    int i = blockIdx.x * blockDim.x + threadIdx.x;
    if (i < E) atomicAdd(&counts[dst[i]], 1);
}

__global__ void scan1_kernel(const int* __restrict__ in, int n, int* __restrict__ bsums) {
    __shared__ int sdata[256];
    int tid = threadIdx.x;
    int base = blockIdx.x * 1024 + tid * 4;
    int s = 0;
#pragma unroll
    for (int j = 0; j < 4; ++j) if (base + j < n) s += in[base + j];
    sdata[tid] = s; __syncthreads();
    for (int off = 128; off > 0; off >>= 1) {
        if (tid < off) sdata[tid] += sdata[tid + off];
        __syncthreads();
    }
    if (tid == 0) bsums[blockIdx.x] = sdata[0];
}

// parallel exclusive scan of nb (<=128) block sums
__global__ void scan2_kernel(int* bsums, int nb) {
    __shared__ int sd[128];
    int tid = threadIdx.x;
    int v = (tid < nb) ? bsums[tid] : 0;
    sd[tid] = v; __syncthreads();
    for (int off = 1; off < 128; off <<= 1) {
        int t = (tid >= off) ? sd[tid - off] : 0;
        __syncthreads();
        sd[tid] += t;
        __syncthreads();
    }
    if (tid < nb) bsums[tid] = sd[tid] - v;  // exclusive
}

__global__ void scan3_kernel(const int* __restrict__ in, int n, const int* __restrict__ bsums,
                             int* __restrict__ row_ptr, int* __restrict__ cursor, int E) {
    __shared__ int sdata[256];
    int tid = threadIdx.x;
    int base = blockIdx.x * 1024 + tid * 4;
    int v[4]; int s = 0;
#pragma unroll
    for (int j = 0; j < 4; ++j) { v[j] = (base + j < n) ? in[base + j] : 0; s += v[j]; }
    sdata[tid] = s; __syncthreads();
    for (int off = 1; off < 256; off <<= 1) {
        int t = (tid >= off) ? sdata[tid - off] : 0;
        __syncthreads();
        sdata[tid] += t;
        __syncthreads();
    }
    int excl = sdata[tid] - s;
    int run = bsums[blockIdx.x] + excl;
#pragma unroll
    for (int j = 0; j < 4; ++j) {
        if (base + j < n) { row_ptr[base + j] = run; cursor[base + j] = run; run += v[j]; }
    }
    if (blockIdx.x == 0 && tid == 0) row_ptr[n] = E;
}

__global__ void fill_kernel(const int* __restrict__ dst, const int* __restrict__ src, int E,
                            int* __restrict__ cursor, int* __restrict__ sperm) {
    int i = blockIdx.x * blockDim.x + threadIdx.x;
    if (i < E) {
        int p = atomicAdd(&cursor[dst[i]], 1);
        sperm[p] = src[i];
    }
}

// ======================= prep: all weight transposes + waSD dots, one dispatch =======================

__global__ __launch_bounds__(256) void prep_kernel(
    const float* __restrict__ W0, const float* __restrict__ W1, const float* __restrict__ W2,
    const float* __restrict__ a0, const float* __restrict__ a1, const float* __restrict__ a2,
    unsigned short* __restrict__ WT0, unsigned short* __restrict__ WT1, unsigned short* __restrict__ WT2,
    unsigned short* __restrict__ wa0, unsigned short* __restrict__ wa1, unsigned short* __restrict__ wa2) {
    int i = blockIdx.x * 256 + threadIdx.x;
    if (i < 32768) {                    // W0 [128][256] -> WT0 [256][128]
        int k = i >> 8, n = i & 255;
        WT0[n * 128 + k] = f2bf(W0[i]);
    } else if (i < 98304) {             // W1 [256][256] -> WT1 [256][256]
        int j = i - 32768;
        int k = j >> 8, n = j & 255;
        WT1[n * 256 + k] = f2bf(W1[j]);
    } else if (i < 114688) {            // W2 [256][64] -> WT2 [64][256]
        int j = i - 98304;
        int k = j >> 6, n = j & 63;
        WT2[n * 256 + k] = f2bf(W2[j]);
    } else if (i < 114688 + 2048) {     // wa0 [16][128]
        int t = i - 114688;
        int k = t >> 4, j8 = t & 15;
        float s = 0.f;
        if (j8 < 8) {
            int h = j8 & 3, off = (j8 >> 2) * 64;
            for (int d = 0; d < 64; ++d)
                s += W0[k * 256 + h * 64 + d] * a0[h * 128 + off + d];
        }
        wa0[j8 * 128 + k] = f2bf(s);
    } else if (i < 114688 + 2048 + 4096) {  // wa1 [16][256]
        int t = i - 114688 - 2048;
        int k = t >> 4, j8 = t & 15;
        float s = 0.f;
        if (j8 < 8) {
            int h = j8 & 3, off = (j8 >> 2) * 64;
            for (int d = 0; d < 64; ++d)
                s += W1[k * 256 + h * 64 + d] * a1[h * 128 + off + d];
        }
        wa1[j8 * 256 + k] = f2bf(s);
    } else if (i < 114688 + 2048 + 4096 + 4096) {  // wa2 [16][256]
        int t = i - 114688 - 2048 - 4096;
        int k = t >> 4, j8 = t & 15;
        float s = 0.f;
        if (j8 < 2) {
            for (int d = 0; d < 64; ++d)
                s += W2[k * 64 + d] * a2[j8 * 64 + d];
        }
        wa2[j8 * 256 + k] = f2bf(s);
    }
}

// fp32 -> bf16 elementwise (layer-0 input)
__global__ void xcvt_kernel(const float* __restrict__ X, unsigned short* __restrict__ b, int total) {
    int i = blockIdx.x * 256 + threadIdx.x;
    if (i >= total) return;
    b[i] = f2bf(X[i]);
}

// ======================= fused MFMA GEMM + alpha-via-MFMA + fp16-emit =======================

template <int BN>
__global__ __launch_bounds__(256) void gemm_fused(
    const unsigned short* __restrict__ A, const unsigned short* __restrict__ WT,
    const unsigned short* __restrict__ waSDT,
    unsigned short* __restrict__ hf16,
    float* __restrict__ as_, float* __restrict__ ad_,
    int M, int K) {
    __shared__ unsigned short AL[128 * 32];
    __shared__ unsigned short BL[BN * 32];
    __shared__ unsigned short WaL[16 * 32];

    int t = threadIdx.x;
    int w = t >> 6, lane = t & 63;
    int q = lane >> 4, i16 = lane & 15;
    int rowBase = blockIdx.x * 128;
    int colBase = blockIdx.y * BN;

    constexpr int MT = (BN == 128) ? 4 : 2;
    int wrow = (BN == 128) ? (w >> 1) * 64 : w * 32;
    int wcol = (BN == 128) ? (w & 1) * 64 : 0;

    bool alphaBlk = (blockIdx.y == 0);
    bool alphaWave = alphaBlk && ((BN == 64) || ((w & 1) == 0));

    float4v acc[MT][4];
    float4v accA[MT];
#pragma unroll
    for (int mt = 0; mt < MT; ++mt) {
        accA[mt] = (float4v)(0.f);
#pragma unroll
        for (int nt = 0; nt < 4; ++nt) acc[mt][nt] = (float4v)(0.f);
    }

    int srow = t >> 2;          // 0..63
    int skq = (t & 3) * 8;      // k offset in shorts (16B chunks)

    for (int k0 = 0; k0 < K; k0 += 32) {
        gload_lds16(A + (size_t)(rowBase + srow) * K + k0 + skq, AL + w * 512);
        gload_lds16(A + (size_t)(rowBase + 64 + srow) * K + k0 + skq, AL + 2048 + w * 512);
        gload_lds16(WT + (size_t)(colBase + srow) * K + k0 + skq, BL + w * 512);
        if (BN == 128)
            gload_lds16(WT + (size_t)(colBase + 64 + srow) * K + k0 + skq, BL + 2048 + w * 512);
        if (alphaBlk && w == 0)  // 16 rows x 32 k = 1 KB = one wave's gload
            gload_lds16(waSDT + (size_t)srow * K + k0 + skq, WaL);
        __syncthreads();

        short8 af[MT], bf[4];
#pragma unroll
        for (int mt = 0; mt < MT; ++mt)
            af[mt] = *(short8*)&AL[(wrow + mt * 16 + i16) * 32 + q * 8];
#pragma unroll
        for (int nt = 0; nt < 4; ++nt)
            bf[nt] = *(short8*)&BL[(wcol + nt * 16 + i16) * 32 + q * 8];
#pragma unroll
        for (int mt = 0; mt < MT; ++mt)
#pragma unroll
            for (int nt = 0; nt < 4; ++nt)
                acc[mt][nt] = __builtin_amdgcn_mfma_f32_16x16x32_bf16(af[mt], bf[nt], acc[mt][nt], 0, 0, 0);
        if (alphaWave) {
            short8 aw = *(short8*)&WaL[i16 * 32 + q * 8];
#pragma unroll
            for (int mt = 0; mt < MT; ++mt)
                accA[mt] = __builtin_amdgcn_mfma_f32_16x16x32_bf16(af[mt], aw, accA[mt], 0, 0, 0);
        }
        __syncthreads();
    }

    // ---- epilogue: C/D layout col=lane&15, row=q*4+r ----
    int cb0 = colBase + wcol;
#pragma unroll
    for (int mt = 0; mt < MT; ++mt)
#pragma unroll
        for (int r = 0; r < 4; ++r) {
            int grow = rowBase + wrow + mt * 16 + q * 4 + r;
            bool ok = grow < M;
            if (ok) {
#pragma unroll
                for (int nt = 0; nt < 4; ++nt) {
                    float v = acc[mt][nt][r];
                    if (BN == 128) hf16[(size_t)grow * 256 + cb0 + nt * 16 + i16] = f2h(v);
                    else           hf16[(size_t)grow * 64 + nt * 16 + i16] = f2h(v);
                }
                if (alphaWave) {
                    float av = accA[mt][r];
                    if (BN == 128) {
                        if (i16 < 4)      as_[grow * 4 + i16] = av;
                        else if (i16 < 8) ad_[grow * 4 + (i16 - 4)] = av;
                    } else {
                        if (i16 == 0)      as_[grow] = av;
                        else if (i16 == 1) ad_[grow] = av;
                    }
                }
            }
        }
}

// ======================= aggregate H=4, fp16 messages, single-pass softmax =======================
// 1 node/wave (36 VGPR, max occupancy). NT loads for read-once sperm, NT stores for output:
// keeps dead streams out of the 4MiB/XCD L2 so its capacity serves the h-row gathers.

__global__ __launch_bounds__(256) void aggregate4(
    const unsigned short* __restrict__ hf16, const int* __restrict__ row_ptr,
    const int* __restrict__ sperm, const float* __restrict__ as_, const float* __restrict__ ad_,
    unsigned short* __restrict__ outB, int n) {
    int w = threadIdx.x >> 6, lane = threadIdx.x & 63;
    int node = blockIdx.x * 4 + w;
    if (node >= n) return;
    int beg = row_ptr[node], end = row_ptr[node + 1];
    int deg = end - beg;
    int myh = lane & 3;
    float ad_my = ad_[node * 4 + myh];

    int half = lane >> 5;     // edge parity this lane aggregates
    int dg = lane & 31;       // dim group: dims dg*8..dg*8+7
    int hh = dg >> 3;         // head of those dims
    float acc[8];
#pragma unroll
    for (int k = 0; k < 8; ++k) acc[k] = 0.f;
    float lsum = 0.f;         // unnormalized denom partial for head myh

    const char* hbase = (const char*)hf16;
    unsigned dgo = (unsigned)dg << 4;

    for (int el0 = 0; el0 < deg; el0 += 16) {
        int ne = deg - el0; if (ne > 16) ne = 16;
        int eSlot = lane >> 2;
        float att = 0.f; int sMy = 0;
        if (eSlot < ne) {
            sMy = __builtin_nontemporal_load(&sperm[beg + el0 + eSlot]);
            float e = as_[sMy * 4 + myh] + ad_my;
            e = e > 0.f ? e : NEG_SLOPE * e;
            att = __expf(e);
        }
        lsum += att;

        int j = 0;
        for (; j + 8 <= ne; j += 8) {
            int sl0 = j + half, sl1 = j + 2 + half, sl2 = j + 4 + half, sl3 = j + 6 + half;
            float a0 = __shfl(att, sl0 * 4 + hh, 64);
            int   s0 = __shfl(sMy, sl0 * 4, 64);
            float a1 = __shfl(att, sl1 * 4 + hh, 64);
            int   s1 = __shfl(sMy, sl1 * 4, 64);
            float a2 = __shfl(att, sl2 * 4 + hh, 64);
            int   s2 = __shfl(sMy, sl2 * 4, 64);
            float a3 = __shfl(att, sl3 * 4 + hh, 64);
            int   s3 = __shfl(sMy, sl3 * 4, 64);
            h8 v0 = *(const h8*)(hbase + (((unsigned)s0 << 9) + dgo));
            h8 v1 = *(const h8*)(hbase + (((unsigned)s1 << 9) + dgo));
            h8 v2 = *(const h8*)(hbase + (((unsigned)s2 << 9) + dgo));
            h8 v3 = *(const h8*)(hbase + (((unsigned)s3 << 9) + dgo));
#pragma unroll
            for (int k = 0; k < 8; ++k) acc[k] += a0 * (float)v0[k];
#pragma unroll
            for (int k = 0; k < 8; ++k) acc[k] += a1 * (float)v1[k];
#pragma unroll
            for (int k = 0; k < 8; ++k) acc[k] += a2 * (float)v2[k];
#pragma unroll
            for (int k = 0; k < 8; ++k) acc[k] += a3 * (float)v3[k];
        }
        for (; j < ne; j += 2) {
            int sl = j + half;  // slot >= ne in odd tail -> att==0 (adds exact 0)
            float a = __shfl(att, sl * 4 + hh, 64);
            int   s = __shfl(sMy, sl * 4, 64);
            h8 v = *(const h8*)(hbase + (((unsigned)s << 9) + dgo));
#pragma unroll
            for (int k = 0; k < 8; ++k) acc[k] += a * (float)v[k];
        }
    }

    // total denom per head: sum lanes with same (lane&3)
#pragma unroll
    for (int m = 4; m < 64; m <<= 1) lsum += __shfl_xor(lsum, m, 64);
    float inv = 1.f / (lsum + 1e-16f);
    float invh = __shfl(inv, hh, 64);

#pragma unroll
    for (int k = 0; k < 8; ++k) {
        acc[k] += __shfl_xor(acc[k], 32, 64);
        acc[k] *= invh;
    }

    if (half == 0) {
        short8 hv;
#pragma unroll
        for (int k = 0; k < 8; ++k) {
            float o = acc[k] > 0.f ? acc[k] : (__expf(acc[k]) - 1.f);
            hv[k] = (short)f2bf(o);
        }
        __builtin_nontemporal_store(hv, (short8*)(outB + (size_t)node * 256 + dg * 8));
    }
}

// ======================= aggregate H=1, single-pass, fp32 out (graded) =======================

__global__ __launch_bounds__(256) void aggregate1(
    const unsigned short* __restrict__ hf16, const int* __restrict__ row_ptr,
    const int* __restrict__ sperm, const float* __restrict__ as_, const float* __restrict__ ad_,
    float* __restrict__ out, int n) {
    int w = threadIdx.x >> 6, lane = threadIdx.x & 63;
    int node = blockIdx.x * 4 + w;
    if (node >= n) return;
    int beg = row_ptr[node], end = row_ptr[node + 1];
    int deg = end - beg;
    float ad_n = ad_[node];

    int eg = lane >> 3;   // edge slot within 8-edge subgroup
    int dg = lane & 7;    // dims dg*8..+8
    float acc[8];
#pragma unroll
    for (int k = 0; k < 8; ++k) acc[k] = 0.f;
    float lsum = 0.f;

    const char* hbase = (const char*)hf16;
    unsigned dgo = (unsigned)dg << 4;

    for (int el0 = 0; el0 < deg; el0 += 64) {
        int ne = deg - el0; if (ne > 64) ne = 64;
        float att = 0.f; int sMy = 0;
        if (lane < ne) {
            sMy = __builtin_nontemporal_load(&sperm[beg + el0 + lane]);
            float e = as_[sMy] + ad_n;
            e = e > 0.f ? e : NEG_SLOPE * e;
            att = __expf(e);
        }
        lsum += att;

        int j = 0;
        for (; j + 32 <= ne; j += 32) {
            int sl0 = j + eg, sl1 = j + 8 + eg, sl2 = j + 16 + eg, sl3 = j + 24 + eg;
            float a0 = __shfl(att, sl0, 64);
            int   s0 = __shfl(sMy, sl0, 64);
            float a1 = __shfl(att, sl1, 64);
            int   s1 = __shfl(sMy, sl1, 64);
            float a2 = __shfl(att, sl2, 64);
            int   s2 = __shfl(sMy, sl2, 64);
            float a3 = __shfl(att, sl3, 64);
            int   s3 = __shfl(sMy, sl3, 64);
            h8 v0 = *(const h8*)(hbase + (((unsigned)s0 << 7) + dgo));
            h8 v1 = *(const h8*)(hbase + (((unsigned)s1 << 7) + dgo));
            h8 v2 = *(const h8*)(hbase + (((unsigned)s2 << 7) + dgo));
            h8 v3 = *(const h8*)(hbase + (((unsigned)s3 << 7) + dgo));
#pragma unroll
            for (int k = 0; k < 8; ++k) acc[k] += a0 * (float)v0[k];
#pragma unroll
            for (int k = 0; k < 8; ++k) acc[k] += a1 * (float)v1[k];
#pragma unroll
            for (int k = 0; k < 8; ++k) acc[k] += a2 * (float)v2[k];
#pragma unroll
            for (int k = 0; k < 8; ++k) acc[k] += a3 * (float)v3[k];
        }
        for (; j < ne; j += 8) {
            int sl = j + eg;
            float a = __shfl(att, sl, 64);
            int   s = __shfl(sMy, sl, 64);
            h8 v = *(const h8*)(hbase + (((unsigned)s << 7) + dgo));
#pragma unroll
            for (int k = 0; k < 8; ++k) acc[k] += a * (float)v[k];
        }
    }

#pragma unroll
    for (int m = 1; m < 64; m <<= 1) lsum += __shfl_xor(lsum, m, 64);
    float inv = 1.f / (lsum + 1e-16f);

#pragma unroll
    for (int m = 8; m < 64; m <<= 1)
#pragma unroll
        for (int k = 0; k < 8; ++k) acc[k] += __shfl_xor(acc[k], m, 64);

    if (eg == 0) {
        float4v o0, o1;
        o0[0] = acc[0] * inv; o0[1] = acc[1] * inv; o0[2] = acc[2] * inv; o0[3] = acc[3] * inv;
        o1[0] = acc[4] * inv; o1[1] = acc[5] * inv; o1[2] = acc[6] * inv; o1[3] = acc[7] * inv;
        __builtin_nontemporal_store(o0, (float4v*)(out + (size_t)node * 64 + dg * 8));
        __builtin_nontemporal_store(o1, (float4v*)(out + (size_t)node * 64 + dg * 8 + 4));
    }
}

// ======================= launch =======================

extern "C" void kernel_launch(void* const* d_in, const int* in_sizes, int n_in,
                              void* d_out, int out_size, void* d_ws, size_t ws_size,
                              hipStream_t stream) {
    const float* x  = (const float*)d_in[0];
    const int*   ei = (const int*)d_in[1];
    const float* W0 = (const float*)d_in[2];
    const float* a0 = (const float*)d_in[3];
    const float* W1 = (const float*)d_in[4];
    const float* a1 = (const float*)d_in[5];
    const float* W2 = (const float*)d_in[6];
    const float* a2 = (const float*)d_in[7];
    float* out = (float*)d_out;

    int N = in_sizes[0] / 128;
    int E = in_sizes[1] / 2;
    int Npad = (N + 127) & ~127;
    const int* srcp = ei;
    const int* dstp = ei + E;

    char* ws = (char*)d_ws;
    size_t off = 0;
    auto alloc = [&](size_t bytes) -> void* {
        void* p = ws + off;
        off += (bytes + 255) & ~(size_t)255;
        return p;
    };
    unsigned short* xbf  = (unsigned short*)alloc((size_t)Npad * 128 * 2);
    unsigned short* actB = (unsigned short*)alloc((size_t)Npad * 256 * 2);
    unsigned short* hf16 = (unsigned short*)alloc((size_t)Npad * 256 * 2);
    unsigned short* Cf16 = (unsigned short*)alloc((size_t)Npad * 64 * 2);
    float* as_    = (float*)alloc((size_t)N * 4 * 4);
    float* ad_    = (float*)alloc((size_t)N * 4 * 4);
    int*   counts = (int*)alloc((size_t)N * 4);
    int*   row_ptr= (int*)alloc((size_t)(N + 1) * 4);
    int*   cursor = (int*)alloc((size_t)N * 4);
    int*   sperm  = (int*)alloc((size_t)E * 4);
    unsigned short* WT0 = (unsigned short*)alloc((size_t)256 * 128 * 2);
    unsigned short* WT1 = (unsigned short*)alloc((size_t)256 * 256 * 2);
    unsigned short* WT2 = (unsigned short*)alloc((size_t)64 * 256 * 2);
    unsigned short* wa0 = (unsigned short*)alloc((size_t)16 * 128 * 2);
    unsigned short* wa1 = (unsigned short*)alloc((size_t)16 * 256 * 2);
    unsigned short* wa2 = (unsigned short*)alloc((size_t)16 * 256 * 2);
    int*   bsums  = (int*)alloc(4096);

    // ---- CSR by dst ----
    hipMemsetAsync(counts, 0, (size_t)N * 4, stream);
    int egrid = (E + 255) / 256;
    count_kernel<<<egrid, 256, 0, stream>>>(dstp, E, counts);
    int nb = (N + 1023) / 1024;
    scan1_kernel<<<nb, 256, 0, stream>>>(counts, N, bsums);
    scan2_kernel<<<1, 128, 0, stream>>>(bsums, nb);
    scan3_kernel<<<nb, 256, 0, stream>>>(counts, N, bsums, row_ptr, cursor, E);
    fill_kernel<<<egrid, 256, 0, stream>>>(dstp, srcp, E, cursor, sperm);

    // ---- prep: all W transposes + waSD, one dispatch ----
    prep_kernel<<<(114688 + 10240 + 255) / 256, 256, 0, stream>>>(
        W0, W1, W2, a0, a1, a2, WT0, WT1, WT2, wa0, wa1, wa2);
    xcvt_kernel<<<((N * 128) + 255) / 256, 256, 0, stream>>>(x, xbf, N * 128);

    int gemm_gx = Npad / 128;
    int ngrid4 = (N + 3) / 4;

    // ---- Layer 0 ----
    gemm_fused<128><<<dim3(gemm_gx, 2), 256, 0, stream>>>(xbf, WT0, wa0, hf16, as_, ad_, N, 128);
    aggregate4<<<ngrid4, 256, 0, stream>>>(hf16, row_ptr, sperm, as_, ad_, actB, N);

    // ---- Layer 1 ----
    gemm_fused<128><<<dim3(gemm_gx, 2), 256, 0, stream>>>(actB, WT1, wa1, hf16, as_, ad_, N, 256);
    aggregate4<<<ngrid4, 256, 0, stream>>>(hf16, row_ptr, sperm, as_, ad_, actB, N);

    // ---- Layer 2 ----
    gemm_fused<64><<<dim3(gemm_gx, 1), 256, 0, stream>>>(actB, WT2, wa2, Cf16, as_, ad_, N, 256);
    aggregate1<<<ngrid4, 256, 0, stream>>>(Cf16, row_ptr, sperm, as_, ad_, out, N);
}

// Round 4
// 574.870 us; speedup vs baseline: 1.2333x; 1.2279x over previous
//
#include <hip/hip_runtime.h>
#include <math.h>

#define NEG_SLOPE 0.2f
#define SCHUNK 4096

typedef short short8 __attribute__((ext_vector_type(8)));
typedef float float4v __attribute__((ext_vector_type(4)));
typedef int int2v __attribute__((ext_vector_type(2)));
typedef _Float16 h8 __attribute__((ext_vector_type(8)));

__device__ __forceinline__ unsigned short f2bf(float f) {
    unsigned u = __float_as_uint(f);
    unsigned r = (u + 0x7fff + ((u >> 16) & 1)) >> 16;
    return (unsigned short)r;
}
__device__ __forceinline__ float bf2f(unsigned short h) {
    return __uint_as_float(((unsigned)h) << 16);
}
__device__ __forceinline__ unsigned short f2h(float f) {
    _Float16 t = (_Float16)f;
    return *(unsigned short*)&t;
}

// async global->LDS, 16B per lane. ldsptr must be wave-uniform; HW adds lane*16.
__device__ __forceinline__ void gload_lds16(const void* g, void* l) {
    __builtin_amdgcn_global_load_lds(
        (const __attribute__((address_space(1))) unsigned int*)g,
        (__attribute__((address_space(3))) unsigned int*)l, 16, 0, 0);
}

// ======================= atomic-free CSR build (two-level MSD bucket sort) =======================
// Pass 1: bin edges by dst>>9 into NBUCK (<=256) coarse buckets.
//   hist_kernel: per-block LDS histogram -> H[bucket*B1 + block]
//   scan1/2/3g:  exclusive scan of H (bucket-major) -> Hs (global scatter offsets)
//   scatter_kernel: LDS cursors from Hs, write packed (dst,src) into tmp
// Pass 2: bucket_kernel, one block per bucket: 512-bin LDS histogram of its segment,
//   LDS scan -> row_ptr for its 512 nodes (no global count/scan needed), then LDS-cursor
//   scatter of src into sperm. Zero global atomics anywhere.

__global__ __launch_bounds__(256) void hist_kernel(const int* __restrict__ dst, int E,
                                                   int NBUCK, int B1, int* __restrict__ H) {
    __shared__ int hist[256];
    int tid = threadIdx.x;
    for (int j = tid; j < NBUCK; j += 256) hist[j] = 0;
    __syncthreads();
    int base = blockIdx.x * SCHUNK;
    int endi = base + SCHUNK; if (endi > E) endi = E;
    for (int i = base + tid; i < endi; i += 256)
        atomicAdd(&hist[dst[i] >> 9], 1);
    __syncthreads();
    for (int j = tid; j < NBUCK; j += 256)
        H[j * B1 + blockIdx.x] = hist[j];
}

__global__ void scan1_kernel(const int* __restrict__ in, int n, int* __restrict__ bsums) {
    __shared__ int sdata[256];
    int tid = threadIdx.x;
    int base = blockIdx.x * 1024 + tid * 4;
    int s = 0;
#pragma unroll
    for (int j = 0; j < 4; ++j) if (base + j < n) s += in[base + j];
    sdata[tid] = s; __syncthreads();
    for (int off = 128; off > 0; off >>= 1) {
        if (tid < off) sdata[tid] += sdata[tid + off];
        __syncthreads();
    }
    if (tid == 0) bsums[blockIdx.x] = sdata[0];
}

// parallel exclusive scan of nb (<=128) block sums
__global__ void scan2_kernel(int* bsums, int nb) {
    __shared__ int sd[128];
    int tid = threadIdx.x;
    int v = (tid < nb) ? bsums[tid] : 0;
    sd[tid] = v; __syncthreads();
    for (int off = 1; off < 128; off <<= 1) {
        int t = (tid >= off) ? sd[tid - off] : 0;
        __syncthreads();
        sd[tid] += t;
        __syncthreads();
    }
    if (tid < nb) bsums[tid] = sd[tid] - v;  // exclusive
}

// exclusive scan output into outs[] (generic)
__global__ void scan3g_kernel(const int* __restrict__ in, int n, const int* __restrict__ bsums,
                              int* __restrict__ outs) {
    __shared__ int sdata[256];
    int tid = threadIdx.x;
    int base = blockIdx.x * 1024 + tid * 4;
    int v[4]; int s = 0;
#pragma unroll
    for (int j = 0; j < 4; ++j) { v[j] = (base + j < n) ? in[base + j] : 0; s += v[j]; }
    sdata[tid] = s; __syncthreads();
    for (int off = 1; off < 256; off <<= 1) {
        int t = (tid >= off) ? sdata[tid - off] : 0;
        __syncthreads();
        sdata[tid] += t;
        __syncthreads();
    }
    int excl = sdata[tid] - s;
    int run = bsums[blockIdx.x] + excl;
#pragma unroll
    for (int j = 0; j < 4; ++j) {
        if (base + j < n) { outs[base + j] = run; run += v[j]; }
    }
}

__global__ __launch_bounds__(256) void scatter_kernel(
    const int* __restrict__ dst, const int* __restrict__ src, int E,
    int NBUCK, int B1, const int* __restrict__ Hs, int2v* __restrict__ tmp) {
    __shared__ int curs[256];
    int tid = threadIdx.x;
    for (int j = tid; j < NBUCK; j += 256) curs[j] = Hs[j * B1 + blockIdx.x];
    __syncthreads();
    int base = blockIdx.x * SCHUNK;
    int endi = base + SCHUNK; if (endi > E) endi = E;
    for (int i = base + tid; i < endi; i += 256) {
        int d = dst[i], sv = src[i];
        int p = atomicAdd(&curs[d >> 9], 1);
        int2v pr; pr[0] = d; pr[1] = sv;
        tmp[p] = pr;
    }
}

__global__ __launch_bounds__(256) void bucket_kernel(
    const int2v* __restrict__ tmp, const int* __restrict__ Hs,
    int B1, int NBUCK, int E, int n,
    int* __restrict__ row_ptr, int* __restrict__ sperm) {
    int b = blockIdx.x, tid = threadIdx.x;
    int s = Hs[b * B1];
    int e = (b + 1 < NBUCK) ? Hs[(b + 1) * B1] : E;
    int base = b << 9;
    __shared__ int hist[512];
    __shared__ int scanv[512];
    __shared__ int psum[256];
    hist[tid] = 0; hist[tid + 256] = 0;
    __syncthreads();
    for (int i = s + tid; i < e; i += 256)
        atomicAdd(&hist[tmp[i][0] - base], 1);
    __syncthreads();
    int a = hist[2 * tid], c = hist[2 * tid + 1];
    psum[tid] = a + c;
    __syncthreads();
    for (int off = 1; off < 256; off <<= 1) {
        int t = (tid >= off) ? psum[tid - off] : 0;
        __syncthreads();
        psum[tid] += t;
        __syncthreads();
    }
    int excl = psum[tid] - (a + c);
    scanv[2 * tid] = excl;
    scanv[2 * tid + 1] = excl + a;
    __syncthreads();
    // row_ptr for this bucket's nodes (offset of first edge of each node)
    for (int j = tid; j < 512; j += 256) {
        int node = base + j;
        if (node < n) row_ptr[node] = s + scanv[j];
    }
    if (b == 0 && tid == 0) row_ptr[n] = E;
    __syncthreads();
    // scatter src into grouped positions (LDS cursors = scanv, mutated)
    for (int i = s + tid; i < e; i += 256) {
        int2v pr = tmp[i];
        int p = s + atomicAdd(&scanv[pr[0] - base], 1);
        sperm[p] = pr[1];
    }
}

// ======================= prep: all weight transposes + waSD dots, one dispatch =======================

__global__ __launch_bounds__(256) void prep_kernel(
    const float* __restrict__ W0, const float* __restrict__ W1, const float* __restrict__ W2,
    const float* __restrict__ a0, const float* __restrict__ a1, const float* __restrict__ a2,
    unsigned short* __restrict__ WT0, unsigned short* __restrict__ WT1, unsigned short* __restrict__ WT2,
    unsigned short* __restrict__ wa0, unsigned short* __restrict__ wa1, unsigned short* __restrict__ wa2) {
    int i = blockIdx.x * 256 + threadIdx.x;
    if (i < 32768) {                    // W0 [128][256] -> WT0 [256][128]
        int k = i >> 8, n = i & 255;
        WT0[n * 128 + k] = f2bf(W0[i]);
    } else if (i < 98304) {             // W1 [256][256] -> WT1 [256][256]
        int j = i - 32768;
        int k = j >> 8, n = j & 255;
        WT1[n * 256 + k] = f2bf(W1[j]);
    } else if (i < 114688) {            // W2 [256][64] -> WT2 [64][256]
        int j = i - 98304;
        int k = j >> 6, n = j & 63;
        WT2[n * 256 + k] = f2bf(W2[j]);
    } else if (i < 114688 + 2048) {     // wa0 [16][128]
        int t = i - 114688;
        int k = t >> 4, j8 = t & 15;
        float s = 0.f;
        if (j8 < 8) {
            int h = j8 & 3, off = (j8 >> 2) * 64;
            for (int d = 0; d < 64; ++d)
                s += W0[k * 256 + h * 64 + d] * a0[h * 128 + off + d];
        }
        wa0[j8 * 128 + k] = f2bf(s);
    } else if (i < 114688 + 2048 + 4096) {  // wa1 [16][256]
        int t = i - 114688 - 2048;
        int k = t >> 4, j8 = t & 15;
        float s = 0.f;
        if (j8 < 8) {
            int h = j8 & 3, off = (j8 >> 2) * 64;
            for (int d = 0; d < 64; ++d)
                s += W1[k * 256 + h * 64 + d] * a1[h * 128 + off + d];
        }
        wa1[j8 * 256 + k] = f2bf(s);
    } else if (i < 114688 + 2048 + 4096 + 4096) {  // wa2 [16][256]
        int t = i - 114688 - 2048 - 4096;
        int k = t >> 4, j8 = t & 15;
        float s = 0.f;
        if (j8 < 2) {
            for (int d = 0; d < 64; ++d)
                s += W2[k * 64 + d] * a2[j8 * 64 + d];
        }
        wa2[j8 * 256 + k] = f2bf(s);
    }
}

// fp32 -> bf16 elementwise (layer-0 input)
__global__ void xcvt_kernel(const float* __restrict__ X, unsigned short* __restrict__ b, int total) {
    int i = blockIdx.x * 256 + threadIdx.x;
    if (i >= total) return;
    b[i] = f2bf(X[i]);
}

// ======================= fused MFMA GEMM + alpha-via-MFMA + fp16-emit =======================

template <int BN>
__global__ __launch_bounds__(256) void gemm_fused(
    const unsigned short* __restrict__ A, const unsigned short* __restrict__ WT,
    const unsigned short* __restrict__ waSDT,
    unsigned short* __restrict__ hf16,
    float* __restrict__ as_, float* __restrict__ ad_,
    int M, int K) {
    __shared__ unsigned short AL[128 * 32];
    __shared__ unsigned short BL[BN * 32];
    __shared__ unsigned short WaL[16 * 32];

    int t = threadIdx.x;
    int w = t >> 6, lane = t & 63;
    int q = lane >> 4, i16 = lane & 15;
    int rowBase = blockIdx.x * 128;
    int colBase = blockIdx.y * BN;

    constexpr int MT = (BN == 128) ? 4 : 2;
    int wrow = (BN == 128) ? (w >> 1) * 64 : w * 32;
    int wcol = (BN == 128) ? (w & 1) * 64 : 0;

    bool alphaBlk = (blockIdx.y == 0);
    bool alphaWave = alphaBlk && ((BN == 64) || ((w & 1) == 0));

    float4v acc[MT][4];
    float4v accA[MT];
#pragma unroll
    for (int mt = 0; mt < MT; ++mt) {
        accA[mt] = (float4v)(0.f);
#pragma unroll
        for (int nt = 0; nt < 4; ++nt) acc[mt][nt] = (float4v)(0.f);
    }

    int srow = t >> 2;          // 0..63
    int skq = (t & 3) * 8;      // k offset in shorts (16B chunks)

    for (int k0 = 0; k0 < K; k0 += 32) {
        gload_lds16(A + (size_t)(rowBase + srow) * K + k0 + skq, AL + w * 512);
        gload_lds16(A + (size_t)(rowBase + 64 + srow) * K + k0 + skq, AL + 2048 + w * 512);
        gload_lds16(WT + (size_t)(colBase + srow) * K + k0 + skq, BL + w * 512);
        if (BN == 128)
            gload_lds16(WT + (size_t)(colBase + 64 + srow) * K + k0 + skq, BL + 2048 + w * 512);
        if (alphaBlk && w == 0)  // 16 rows x 32 k = 1 KB = one wave's gload
            gload_lds16(waSDT + (size_t)srow * K + k0 + skq, WaL);
        __syncthreads();

        short8 af[MT], bf[4];
#pragma unroll
        for (int mt = 0; mt < MT; ++mt)
            af[mt] = *(short8*)&AL[(wrow + mt * 16 + i16) * 32 + q * 8];
#pragma unroll
        for (int nt = 0; nt < 4; ++nt)
            bf[nt] = *(short8*)&BL[(wcol + nt * 16 + i16) * 32 + q * 8];
#pragma unroll
        for (int mt = 0; mt < MT; ++mt)
#pragma unroll
            for (int nt = 0; nt < 4; ++nt)
                acc[mt][nt] = __builtin_amdgcn_mfma_f32_16x16x32_bf16(af[mt], bf[nt], acc[mt][nt], 0, 0, 0);
        if (alphaWave) {
            short8 aw = *(short8*)&WaL[i16 * 32 + q * 8];
#pragma unroll
            for (int mt = 0; mt < MT; ++mt)
                accA[mt] = __builtin_amdgcn_mfma_f32_16x16x32_bf16(af[mt], aw, accA[mt], 0, 0, 0);
        }
        __syncthreads();
    }

    // ---- epilogue: C/D layout col=lane&15, row=q*4+r ----
    int cb0 = colBase + wcol;
#pragma unroll
    for (int mt = 0; mt < MT; ++mt)
#pragma unroll
        for (int r = 0; r < 4; ++r) {
            int grow = rowBase + wrow + mt * 16 + q * 4 + r;
            bool ok = grow < M;
            if (ok) {
#pragma unroll
                for (int nt = 0; nt < 4; ++nt) {
                    float v = acc[mt][nt][r];
                    if (BN == 128) hf16[(size_t)grow * 256 + cb0 + nt * 16 + i16] = f2h(v);
                    else           hf16[(size_t)grow * 64 + nt * 16 + i16] = f2h(v);
                }
                if (alphaWave) {
                    float av = accA[mt][r];
                    if (BN == 128) {
                        if (i16 < 4)      as_[grow * 4 + i16] = av;
                        else if (i16 < 8) ad_[grow * 4 + (i16 - 4)] = av;
                    } else {
                        if (i16 == 0)      as_[grow] = av;
                        else if (i16 == 1) ad_[grow] = av;
                    }
                }
            }
        }
}

// ======================= aggregate H=4, fp16 messages, single-pass softmax =======================
// 1 node/wave (36 VGPR, max occupancy). NT loads for read-once sperm, NT stores for output:
// keeps dead streams out of the 4MiB/XCD L2 so its capacity serves the h-row gathers.

__global__ __launch_bounds__(256) void aggregate4(
    const unsigned short* __restrict__ hf16, const int* __restrict__ row_ptr,
    const int* __restrict__ sperm, const float* __restrict__ as_, const float* __restrict__ ad_,
    unsigned short* __restrict__ outB, int n) {
    int w = threadIdx.x >> 6, lane = threadIdx.x & 63;
    int node = blockIdx.x * 4 + w;
    if (node >= n) return;
    int beg = row_ptr[node], end = row_ptr[node + 1];
    int deg = end - beg;
    int myh = lane & 3;
    float ad_my = ad_[node * 4 + myh];

    int half = lane >> 5;     // edge parity this lane aggregates
    int dg = lane & 31;       // dim group: dims dg*8..dg*8+7
    int hh = dg >> 3;         // head of those dims
    float acc[8];
#pragma unroll
    for (int k = 0; k < 8; ++k) acc[k] = 0.f;
    float lsum = 0.f;         // unnormalized denom partial for head myh

    const char* hbase = (const char*)hf16;
    unsigned dgo = (unsigned)dg << 4;

    for (int el0 = 0; el0 < deg; el0 += 16) {
        int ne = deg - el0; if (ne > 16) ne = 16;
        int eSlot = lane >> 2;
        float att = 0.f; int sMy = 0;
        if (eSlot < ne) {
            sMy = __builtin_nontemporal_load(&sperm[beg + el0 + eSlot]);
            float e = as_[sMy * 4 + myh] + ad_my;
            e = e > 0.f ? e : NEG_SLOPE * e;
            att = __expf(e);
        }
        lsum += att;

        int j = 0;
        for (; j + 8 <= ne; j += 8) {
            int sl0 = j + half, sl1 = j + 2 + half, sl2 = j + 4 + half, sl3 = j + 6 + half;
            float a0 = __shfl(att, sl0 * 4 + hh, 64);
            int   s0 = __shfl(sMy, sl0 * 4, 64);
            float a1 = __shfl(att, sl1 * 4 + hh, 64);
            int   s1 = __shfl(sMy, sl1 * 4, 64);
            float a2 = __shfl(att, sl2 * 4 + hh, 64);
            int   s2 = __shfl(sMy, sl2 * 4, 64);
            float a3 = __shfl(att, sl3 * 4 + hh, 64);
            int   s3 = __shfl(sMy, sl3 * 4, 64);
            h8 v0 = *(const h8*)(hbase + (((unsigned)s0 << 9) + dgo));
            h8 v1 = *(const h8*)(hbase + (((unsigned)s1 << 9) + dgo));
            h8 v2 = *(const h8*)(hbase + (((unsigned)s2 << 9) + dgo));
            h8 v3 = *(const h8*)(hbase + (((unsigned)s3 << 9) + dgo));
#pragma unroll
            for (int k = 0; k < 8; ++k) acc[k] += a0 * (float)v0[k];
#pragma unroll
            for (int k = 0; k < 8; ++k) acc[k] += a1 * (float)v1[k];
#pragma unroll
            for (int k = 0; k < 8; ++k) acc[k] += a2 * (float)v2[k];
#pragma unroll
            for (int k = 0; k < 8; ++k) acc[k] += a3 * (float)v3[k];
        }
        for (; j < ne; j += 2) {
            int sl = j + half;  // slot >= ne in odd tail -> att==0 (adds exact 0)
            float a = __shfl(att, sl * 4 + hh, 64);
            int   s = __shfl(sMy, sl * 4, 64);
            h8 v = *(const h8*)(hbase + (((unsigned)s << 9) + dgo));
#pragma unroll
            for (int k = 0; k < 8; ++k) acc[k] += a * (float)v[k];
        }
    }

    // total denom per head: sum lanes with same (lane&3)
#pragma unroll
    for (int m = 4; m < 64; m <<= 1) lsum += __shfl_xor(lsum, m, 64);
    float inv = 1.f / (lsum + 1e-16f);
    float invh = __shfl(inv, hh, 64);

#pragma unroll
    for (int k = 0; k < 8; ++k) {
        acc[k] += __shfl_xor(acc[k], 32, 64);
        acc[k] *= invh;
    }

    if (half == 0) {
        short8 hv;
#pragma unroll
        for (int k = 0; k < 8; ++k) {
            float o = acc[k] > 0.f ? acc[k] : (__expf(acc[k]) - 1.f);
            hv[k] = (short)f2bf(o);
        }
        __builtin_nontemporal_store(hv, (short8*)(outB + (size_t)node * 256 + dg * 8));
    }
}

// ======================= aggregate H=1, single-pass, fp32 out (graded) =======================

__global__ __launch_bounds__(256) void aggregate1(
    const unsigned short* __restrict__ hf16, const int* __restrict__ row_ptr,
    const int* __restrict__ sperm, const float* __restrict__ as_, const float* __restrict__ ad_,
    float* __restrict__ out, int n) {
    int w = threadIdx.x >> 6, lane = threadIdx.x & 63;
    int node = blockIdx.x * 4 + w;
    if (node >= n) return;
    int beg = row_ptr[node], end = row_ptr[node + 1];
    int deg = end - beg;
    float ad_n = ad_[node];

    int eg = lane >> 3;   // edge slot within 8-edge subgroup
    int dg = lane & 7;    // dims dg*8..+8
    float acc[8];
#pragma unroll
    for (int k = 0; k < 8; ++k) acc[k] = 0.f;
    float lsum = 0.f;

    const char* hbase = (const char*)hf16;
    unsigned dgo = (unsigned)dg << 4;

    for (int el0 = 0; el0 < deg; el0 += 64) {
        int ne = deg - el0; if (ne > 64) ne = 64;
        float att = 0.f; int sMy = 0;
        if (lane < ne) {
            sMy = __builtin_nontemporal_load(&sperm[beg + el0 + lane]);
            float e = as_[sMy] + ad_n;
            e = e > 0.f ? e : NEG_SLOPE * e;
            att = __expf(e);
        }
        lsum += att;

        int j = 0;
        for (; j + 32 <= ne; j += 32) {
            int sl0 = j + eg, sl1 = j + 8 + eg, sl2 = j + 16 + eg, sl3 = j + 24 + eg;
            float a0 = __shfl(att, sl0, 64);
            int   s0 = __shfl(sMy, sl0, 64);
            float a1 = __shfl(att, sl1, 64);
            int   s1 = __shfl(sMy, sl1, 64);
            float a2 = __shfl(att, sl2, 64);
            int   s2 = __shfl(sMy, sl2, 64);
            float a3 = __shfl(att, sl3, 64);
            int   s3 = __shfl(sMy, sl3, 64);
            h8 v0 = *(const h8*)(hbase + (((unsigned)s0 << 7) + dgo));
            h8 v1 = *(const h8*)(hbase + (((unsigned)s1 << 7) + dgo));
            h8 v2 = *(const h8*)(hbase + (((unsigned)s2 << 7) + dgo));
            h8 v3 = *(const h8*)(hbase + (((unsigned)s3 << 7) + dgo));
#pragma unroll
            for (int k = 0; k < 8; ++k) acc[k] += a0 * (float)v0[k];
#pragma unroll
            for (int k = 0; k < 8; ++k) acc[k] += a1 * (float)v1[k];
#pragma unroll
            for (int k = 0; k < 8; ++k) acc[k] += a2 * (float)v2[k];
#pragma unroll
            for (int k = 0; k < 8; ++k) acc[k] += a3 * (float)v3[k];
        }
        for (; j < ne; j += 8) {
            int sl = j + eg;
            float a = __shfl(att, sl, 64);
            int   s = __shfl(sMy, sl, 64);
            h8 v = *(const h8*)(hbase + (((unsigned)s << 7) + dgo));
#pragma unroll
            for (int k = 0; k < 8; ++k) acc[k] += a * (float)v[k];
        }
    }

#pragma unroll
    for (int m = 1; m < 64; m <<= 1) lsum += __shfl_xor(lsum, m, 64);
    float inv = 1.f / (lsum + 1e-16f);

#pragma unroll
    for (int m = 8; m < 64; m <<= 1)
#pragma unroll
        for (int k = 0; k < 8; ++k) acc[k] += __shfl_xor(acc[k], m, 64);

    if (eg == 0) {
        float4v o0, o1;
        o0[0] = acc[0] * inv; o0[1] = acc[1] * inv; o0[2] = acc[2] * inv; o0[3] = acc[3] * inv;
        o1[0] = acc[4] * inv; o1[1] = acc[5] * inv; o1[2] = acc[6] * inv; o1[3] = acc[7] * inv;
        __builtin_nontemporal_store(o0, (float4v*)(out + (size_t)node * 64 + dg * 8));
        __builtin_nontemporal_store(o1, (float4v*)(out + (size_t)node * 64 + dg * 8 + 4));
    }
}

// ======================= launch =======================

extern "C" void kernel_launch(void* const* d_in, const int* in_sizes, int n_in,
                              void* d_out, int out_size, void* d_ws, size_t ws_size,
                              hipStream_t stream) {
    const float* x  = (const float*)d_in[0];
    const int*   ei = (const int*)d_in[1];
    const float* W0 = (const float*)d_in[2];
    const float* a0 = (const float*)d_in[3];
    const float* W1 = (const float*)d_in[4];
    const float* a1 = (const float*)d_in[5];
    const float* W2 = (const float*)d_in[6];
    const float* a2 = (const float*)d_in[7];
    float* out = (float*)d_out;

    int N = in_sizes[0] / 128;
    int E = in_sizes[1] / 2;
    int Npad = (N + 127) & ~127;
    const int* srcp = ei;
    const int* dstp = ei + E;

    char* ws = (char*)d_ws;
    size_t off = 0;
    auto alloc = [&](size_t bytes) -> void* {
        void* p = ws + off;
        off += (bytes + 255) & ~(size_t)255;
        return p;
    };
    unsigned short* xbf  = (unsigned short*)alloc((size_t)Npad * 128 * 2);
    unsigned short* actB = (unsigned short*)alloc((size_t)Npad * 256 * 2);
    unsigned short* hf16 = (unsigned short*)alloc((size_t)Npad * 256 * 2);
    unsigned short* Cf16 = (unsigned short*)alloc((size_t)Npad * 64 * 2);
    float* as_    = (float*)alloc((size_t)N * 4 * 4);
    float* ad_    = (float*)alloc((size_t)N * 4 * 4);
    int*   row_ptr= (int*)alloc((size_t)(N + 1) * 4);
    int*   sperm  = (int*)alloc((size_t)E * 4);
    unsigned short* WT0 = (unsigned short*)alloc((size_t)256 * 128 * 2);
    unsigned short* WT1 = (unsigned short*)alloc((size_t)256 * 256 * 2);
    unsigned short* WT2 = (unsigned short*)alloc((size_t)64 * 256 * 2);
    unsigned short* wa0 = (unsigned short*)alloc((size_t)16 * 128 * 2);
    unsigned short* wa1 = (unsigned short*)alloc((size_t)16 * 256 * 2);
    unsigned short* wa2 = (unsigned short*)alloc((size_t)16 * 256 * 2);
    int*   bsums  = (int*)alloc(4096);

    int B1 = (E + SCHUNK - 1) / SCHUNK;          // 391 for E=1.6M
    int NBUCK = (N + 511) >> 9;                  // 196 for N=100k (<=256)
    int Hn = NBUCK * B1;                         // 76,636 (<131072 -> nb<=128)
    int*   H   = (int*)alloc((size_t)Hn * 4);
    int*   Hs  = (int*)alloc((size_t)Hn * 4);
    int2v* tmp = (int2v*)alloc((size_t)E * 8);

    // ---- CSR by dst: atomic-free two-level bucket sort ----
    hist_kernel<<<B1, 256, 0, stream>>>(dstp, E, NBUCK, B1, H);
    int nbH = (Hn + 1023) / 1024;
    scan1_kernel<<<nbH, 256, 0, stream>>>(H, Hn, bsums);
    scan2_kernel<<<1, 128, 0, stream>>>(bsums, nbH);
    scan3g_kernel<<<nbH, 256, 0, stream>>>(H, Hn, bsums, Hs);
    scatter_kernel<<<B1, 256, 0, stream>>>(dstp, srcp, E, NBUCK, B1, Hs, tmp);
    bucket_kernel<<<NBUCK, 256, 0, stream>>>(tmp, Hs, B1, NBUCK, E, N, row_ptr, sperm);

    // ---- prep: all W transposes + waSD, one dispatch ----
    prep_kernel<<<(114688 + 10240 + 255) / 256, 256, 0, stream>>>(
        W0, W1, W2, a0, a1, a2, WT0, WT1, WT2, wa0, wa1, wa2);
    xcvt_kernel<<<((N * 128) + 255) / 256, 256, 0, stream>>>(x, xbf, N * 128);

    int gemm_gx = Npad / 128;
    int ngrid4 = (N + 3) / 4;

    // ---- Layer 0 ----
    gemm_fused<128><<<dim3(gemm_gx, 2), 256, 0, stream>>>(xbf, WT0, wa0, hf16, as_, ad_, N, 128);
    aggregate4<<<ngrid4, 256, 0, stream>>>(hf16, row_ptr, sperm, as_, ad_, actB, N);

    // ---- Layer 1 ----
    gemm_fused<128><<<dim3(gemm_gx, 2), 256, 0, stream>>>(actB, WT1, wa1, hf16, as_, ad_, N, 256);
    aggregate4<<<ngrid4, 256, 0, stream>>>(hf16, row_ptr, sperm, as_, ad_, actB, N);

    // ---- Layer 2 ----
    gemm_fused<64><<<dim3(gemm_gx, 1), 256, 0, stream>>>(actB, WT2, wa2, Cf16, as_, ad_, N, 256);
    aggregate1<<<ngrid4, 256, 0, stream>>>(Cf16, row_ptr, sperm, as_, ad_, out, N);
}